// Round 5
// baseline (443.975 us; speedup 1.0000x reference)
//
#include <hip/hip_runtime.h>

#define HF 64
#define WF 64
#define CCH 512

typedef float f32x4 __attribute__((ext_vector_type(4)));

// f32 -> bf16 round-to-nearest-even
__device__ __forceinline__ unsigned short f32_to_bf16(float f) {
    unsigned int x = __float_as_uint(f);
    unsigned int r = (x + 0x7FFFu + ((x >> 16) & 1u)) >> 16;
    return (unsigned short)r;
}
__device__ __forceinline__ float bf16_to_f32(unsigned short u) {
    return __uint_as_float(((unsigned int)u) << 16);
}

// ---------------- transpose+convert NCHW f32 -> NHWC bf16 -------------------
__global__ __launch_bounds__(256) void nchw_to_nhwc_bf16(const float* __restrict__ src,
                                                         unsigned short* __restrict__ dst) {
    __shared__ float tile[32][33];
    const int hw0 = blockIdx.x * 32;
    const int c0  = blockIdx.y * 32;
    const int b   = blockIdx.z;
    const int tx  = threadIdx.x & 31;
    const int ty  = threadIdx.x >> 5;   // 0..7
    const float*    s = src + (size_t)b * CCH * (HF * WF);
    unsigned short* d = dst + (size_t)b * (HF * WF) * CCH;
#pragma unroll
    for (int i = 0; i < 32; i += 8)
        tile[ty + i][tx] = s[(size_t)(c0 + ty + i) * (HF * WF) + hw0 + tx];
    __syncthreads();
#pragma unroll
    for (int i = 0; i < 32; i += 8)
        d[(size_t)(hw0 + ty + i) * CCH + c0 + tx] = f32_to_bf16(tile[tx][ty + i]);
}

// ---------------- main RoIAlign+avg kernel (NHWC bf16 gather) ---------------
// One block = (roi k, channel chunk of 256). Thread = one channel.
// LDS tile staged in bf16: 256*49*2B = 25.1 KB -> 6 blocks/CU by LDS
// (vs 50.2 KB / 3 blocks for f32 staging) => better gather latency hiding.
__global__ __launch_bounds__(256) void roialign_bf16(const unsigned short* __restrict__ ft,
                                                     const float* __restrict__ rois,
                                                     float* __restrict__ out) {
    __shared__ __align__(16) unsigned short sbuf[256 * 49];

    const int blk   = blockIdx.x;
    const int k     = blk >> 1;
    const int chunk = blk & 1;
    const int tid   = threadIdx.x;
    const int c     = chunk * 256 + tid;

    const float* r = rois + (size_t)k * 5;
    const int   b  = (int)r[0];
    const float x1 = r[1] * 0.0625f;
    const float y1 = r[2] * 0.0625f;
    const float x2 = r[3] * 0.0625f;
    const float y2 = r[4] * 0.0625f;
    const float bin_h = fmaxf(y2 - y1, 0.0f) / 7.0f;
    const float bin_w = fmaxf(x2 - x1, 0.0f) / 7.0f;

    int   hi_[8]; float hr_[8]; float fvh[8];
    int   wi_[8]; float wr_[8]; float fvw[8];
#pragma unroll
    for (int i = 0; i < 8; ++i) {
        float h  = y1 + (float)i * bin_h;
        float hs = fminf(floorf(h), 62.0f);
        hr_[i]   = h - hs;
        hi_[i]   = (int)fminf(fmaxf(hs, 0.0f), 62.0f);
        fvh[i]   = (h >= 0.0f && h < 64.0f) ? 1.0f : 0.0f;
        float w  = x1 + (float)i * bin_w;
        float ws = fminf(floorf(w), 62.0f);
        wr_[i]   = w - ws;
        wi_[i]   = (int)fminf(fmaxf(ws, 0.0f), 62.0f);
        fvw[i]   = (w >= 0.0f && w < 64.0f) ? 1.0f : 0.0f;
    }

    float           prev[8];
    unsigned short* srow = sbuf + tid * 49;

#pragma unroll
    for (int i = 0; i < 8; ++i) {
        float cur[8];
#pragma unroll
        for (int j = 0; j < 8; ++j) {
            const unsigned int o00 =
                (unsigned int)(((b * HF + hi_[i]) * WF + wi_[j]) * CCH + c);
            const float v00 = bf16_to_f32(ft[o00]);
            const float v01 = bf16_to_f32(ft[o00 + CCH]);
            const float v10 = bf16_to_f32(ft[o00 + WF * CCH]);
            const float v11 = bf16_to_f32(ft[o00 + WF * CCH + CCH]);
            const float top = v00 + wr_[j] * (v01 - v00);
            const float bot = v10 + wr_[j] * (v11 - v10);
            const float v   = top + hr_[i] * (bot - top);
            cur[j] = v * (fvh[i] * fvw[j]);
        }
        if (i > 0) {
#pragma unroll
            for (int j = 0; j < 7; ++j)
                srow[(i - 1) * 7 + j] = f32_to_bf16(
                    0.25f * (prev[j] + prev[j + 1] + cur[j] + cur[j + 1]));
        }
#pragma unroll
        for (int j = 0; j < 8; ++j) prev[j] = cur[j];
    }

    __syncthreads();

    // writeout: read 4 bf16 (uint2) from LDS, store float4 (16B coalesced).
    // 12544 bf16 = 3136 uint2 per block.
    float* obase = out + ((size_t)k * CCH + (size_t)chunk * 256) * 49;
    const uint2* s2 = reinterpret_cast<const uint2*>(sbuf);
    f32x4*       o4 = reinterpret_cast<f32x4*>(obase);
    for (int idx = tid; idx < 3136; idx += 256) {
        const uint2 u = s2[idx];
        f32x4 f;
        f.x = bf16_to_f32((unsigned short)(u.x & 0xFFFFu));
        f.y = bf16_to_f32((unsigned short)(u.x >> 16));
        f.z = bf16_to_f32((unsigned short)(u.y & 0xFFFFu));
        f.w = bf16_to_f32((unsigned short)(u.y >> 16));
        o4[idx] = f;
    }
}

// ---------------- fallback: direct NCHW f32 (if ws too small) ---------------
__global__ __launch_bounds__(256) void roialign_f32_nchw(const float* __restrict__ ft,
                                                         const float* __restrict__ rois,
                                                         float* __restrict__ out) {
    __shared__ __align__(16) float sbuf[256 * 49];
    const int blk   = blockIdx.x;
    const int k     = blk >> 1;
    const int chunk = blk & 1;
    const int tid   = threadIdx.x;
    const int c     = chunk * 256 + tid;

    const float* r = rois + (size_t)k * 5;
    const int   b  = (int)r[0];
    const float x1 = r[1] * 0.0625f;
    const float y1 = r[2] * 0.0625f;
    const float x2 = r[3] * 0.0625f;
    const float y2 = r[4] * 0.0625f;
    const float bin_h = fmaxf(y2 - y1, 0.0f) / 7.0f;
    const float bin_w = fmaxf(x2 - x1, 0.0f) / 7.0f;

    int hi_[8]; float hr_[8]; float fvh[8];
    int wi_[8]; float wr_[8]; float fvw[8];
#pragma unroll
    for (int i = 0; i < 8; ++i) {
        float h  = y1 + (float)i * bin_h;
        float hs = fminf(floorf(h), 62.0f);
        hr_[i] = h - hs;
        hi_[i] = (int)fminf(fmaxf(hs, 0.0f), 62.0f);
        fvh[i] = (h >= 0.0f && h < 64.0f) ? 1.0f : 0.0f;
        float w  = x1 + (float)i * bin_w;
        float ws = fminf(floorf(w), 62.0f);
        wr_[i] = w - ws;
        wi_[i] = (int)fminf(fmaxf(ws, 0.0f), 62.0f);
        fvw[i] = (w >= 0.0f && w < 64.0f) ? 1.0f : 0.0f;
    }

    float prev[8];
    float* srow = sbuf + tid * 49;
#pragma unroll
    for (int i = 0; i < 8; ++i) {
        float cur[8];
#pragma unroll
        for (int j = 0; j < 8; ++j) {
            size_t o00 = (size_t)(b * CCH + c) * (HF * WF) + hi_[i] * WF + wi_[j];
            const float v00 = ft[o00];
            const float v01 = ft[o00 + 1];
            const float v10 = ft[o00 + WF];
            const float v11 = ft[o00 + WF + 1];
            const float top = v00 + wr_[j] * (v01 - v00);
            const float bot = v10 + wr_[j] * (v11 - v10);
            const float v   = top + hr_[i] * (bot - top);
            cur[j] = v * (fvh[i] * fvw[j]);
        }
        if (i > 0) {
#pragma unroll
            for (int j = 0; j < 7; ++j)
                srow[(i - 1) * 7 + j] =
                    0.25f * (prev[j] + prev[j + 1] + cur[j] + cur[j + 1]);
        }
#pragma unroll
        for (int j = 0; j < 8; ++j) prev[j] = cur[j];
    }
    __syncthreads();
    float* obase = out + ((size_t)k * CCH + (size_t)chunk * 256) * 49;
    const f32x4* s4 = reinterpret_cast<const f32x4*>(sbuf);
    f32x4*       o4 = reinterpret_cast<f32x4*>(obase);
    for (int idx = tid; idx < 3136; idx += 256) o4[idx] = s4[idx];
}

extern "C" void kernel_launch(void* const* d_in, const int* in_sizes, int n_in,
                              void* d_out, int out_size, void* d_ws, size_t ws_size,
                              hipStream_t stream) {
    const float* feat = (const float*)d_in[0];
    const float* rois = (const float*)d_in[1];
    float*       out  = (float*)d_out;

    const int B = in_sizes[0] / (CCH * HF * WF);
    const int K = in_sizes[1] / 5;

    const size_t featBytes = (size_t)B * CCH * HF * WF * sizeof(unsigned short);
    if (ws_size >= featBytes) {
        unsigned short* ftr = (unsigned short*)d_ws;
        dim3 tg((HF * WF) / 32, CCH / 32, B);
        nchw_to_nhwc_bf16<<<tg, 256, 0, stream>>>(feat, ftr);
        roialign_bf16<<<K * 2, 256, 0, stream>>>(ftr, rois, out);
    } else {
        roialign_f32_nchw<<<K * 2, 256, 0, stream>>>(feat, rois, out);
    }
}

// Round 6
// 72.165 us; speedup vs baseline: 6.1522x; 6.1522x over previous
//
#include <hip/hip_runtime.h>

#define HF 64
#define WF 64
#define CCH 512

// f32 -> bf16 round-to-nearest-even
__device__ __forceinline__ unsigned short f32_to_bf16(float f) {
    unsigned int x = __float_as_uint(f);
    unsigned int r = (x + 0x7FFFu + ((x >> 16) & 1u)) >> 16;
    return (unsigned short)r;
}
__device__ __forceinline__ float bf16_to_f32(unsigned short u) {
    return __uint_as_float(((unsigned int)u) << 16);
}

// ---------------- transpose+convert NCHW f32 -> NHWC bf16 -------------------
__global__ __launch_bounds__(256) void nchw_to_nhwc_bf16(const float* __restrict__ src,
                                                         unsigned short* __restrict__ dst) {
    __shared__ float tile[32][33];
    const int hw0 = blockIdx.x * 32;
    const int c0  = blockIdx.y * 32;
    const int b   = blockIdx.z;
    const int tx  = threadIdx.x & 31;
    const int ty  = threadIdx.x >> 5;   // 0..7
    const float*    s = src + (size_t)b * CCH * (HF * WF);
    unsigned short* d = dst + (size_t)b * (HF * WF) * CCH;
#pragma unroll
    for (int i = 0; i < 32; i += 8)
        tile[ty + i][tx] = s[(size_t)(c0 + ty + i) * (HF * WF) + hw0 + tx];
    __syncthreads();
#pragma unroll
    for (int i = 0; i < 32; i += 8)
        d[(size_t)(hw0 + ty + i) * CCH + c0 + tx] = f32_to_bf16(tile[tx][ty + i]);
}

// ---------------- main RoIAlign+avg kernel (NHWC bf16 gather) ---------------
// One block = (roi k, channel chunk of 256). Thread = one channel.
// NOTE (R5 post-mortem): output tile MUST stay f32 in LDS. Staging it as bf16
// (25 KB) regressed 73 -> 444 us (mechanism unidentified; counters showed
// latency-bound, 580 GB/s). Do not retry without a mechanism.
__global__ __launch_bounds__(256) void roialign_bf16(const unsigned short* __restrict__ ft,
                                                     const float* __restrict__ rois,
                                                     float* __restrict__ out) {
    __shared__ __align__(16) float sbuf[256 * 49];

    const int blk   = blockIdx.x;
    const int k     = blk >> 1;
    const int chunk = blk & 1;
    const int tid   = threadIdx.x;
    const int c     = chunk * 256 + tid;

    const float* r = rois + (size_t)k * 5;
    const int   b  = (int)r[0];
    const float x1 = r[1] * 0.0625f;
    const float y1 = r[2] * 0.0625f;
    const float x2 = r[3] * 0.0625f;
    const float y2 = r[4] * 0.0625f;
    const float bin_h = fmaxf(y2 - y1, 0.0f) / 7.0f;
    const float bin_w = fmaxf(x2 - x1, 0.0f) / 7.0f;

    int   hi_[8]; float hr_[8]; float fvh[8];
    int   wi_[8]; float wr_[8]; float fvw[8];
#pragma unroll
    for (int i = 0; i < 8; ++i) {
        float h  = y1 + (float)i * bin_h;
        float hs = fminf(floorf(h), 62.0f);
        hr_[i]   = h - hs;
        hi_[i]   = (int)fminf(fmaxf(hs, 0.0f), 62.0f);
        fvh[i]   = (h >= 0.0f && h < 64.0f) ? 1.0f : 0.0f;
        float w  = x1 + (float)i * bin_w;
        float ws = fminf(floorf(w), 62.0f);
        wr_[i]   = w - ws;
        wi_[i]   = (int)fminf(fmaxf(ws, 0.0f), 62.0f);
        fvw[i]   = (w >= 0.0f && w < 64.0f) ? 1.0f : 0.0f;
    }

    float  prev[8];
    float* srow = sbuf + tid * 49;

#pragma unroll
    for (int i = 0; i < 8; ++i) {
        float cur[8];
#pragma unroll
        for (int j = 0; j < 8; ++j) {
            const unsigned int o00 =
                (unsigned int)(((b * HF + hi_[i]) * WF + wi_[j]) * CCH + c);
            const float v00 = bf16_to_f32(ft[o00]);
            const float v01 = bf16_to_f32(ft[o00 + CCH]);
            const float v10 = bf16_to_f32(ft[o00 + WF * CCH]);
            const float v11 = bf16_to_f32(ft[o00 + WF * CCH + CCH]);
            const float top = v00 + wr_[j] * (v01 - v00);
            const float bot = v10 + wr_[j] * (v11 - v10);
            const float v   = top + hr_[i] * (bot - top);
            cur[j] = v * (fvh[i] * fvw[j]);
        }
        if (i > 0) {
#pragma unroll
            for (int j = 0; j < 7; ++j)
                srow[(i - 1) * 7 + j] =
                    0.25f * (prev[j] + prev[j + 1] + cur[j] + cur[j + 1]);
        }
#pragma unroll
        for (int j = 0; j < 8; ++j) prev[j] = cur[j];
    }

    __syncthreads();

    // coalesced float4 writeout of the 256x49 tile (12544 floats = 3136 float4)
    float* obase = out + ((size_t)k * CCH + (size_t)chunk * 256) * 49;
    const float4* s4 = reinterpret_cast<const float4*>(sbuf);
    float4*       o4 = reinterpret_cast<float4*>(obase);
    for (int idx = tid; idx < 3136; idx += 256) o4[idx] = s4[idx];
}

// ---------------- fallback: direct NCHW f32 (if ws too small) ---------------
__global__ __launch_bounds__(256) void roialign_f32_nchw(const float* __restrict__ ft,
                                                         const float* __restrict__ rois,
                                                         float* __restrict__ out) {
    __shared__ __align__(16) float sbuf[256 * 49];
    const int blk   = blockIdx.x;
    const int k     = blk >> 1;
    const int chunk = blk & 1;
    const int tid   = threadIdx.x;
    const int c     = chunk * 256 + tid;

    const float* r = rois + (size_t)k * 5;
    const int   b  = (int)r[0];
    const float x1 = r[1] * 0.0625f;
    const float y1 = r[2] * 0.0625f;
    const float x2 = r[3] * 0.0625f;
    const float y2 = r[4] * 0.0625f;
    const float bin_h = fmaxf(y2 - y1, 0.0f) / 7.0f;
    const float bin_w = fmaxf(x2 - x1, 0.0f) / 7.0f;

    int hi_[8]; float hr_[8]; float fvh[8];
    int wi_[8]; float wr_[8]; float fvw[8];
#pragma unroll
    for (int i = 0; i < 8; ++i) {
        float h  = y1 + (float)i * bin_h;
        float hs = fminf(floorf(h), 62.0f);
        hr_[i] = h - hs;
        hi_[i] = (int)fminf(fmaxf(hs, 0.0f), 62.0f);
        fvh[i] = (h >= 0.0f && h < 64.0f) ? 1.0f : 0.0f;
        float w  = x1 + (float)i * bin_w;
        float ws = fminf(floorf(w), 62.0f);
        wr_[i] = w - ws;
        wi_[i] = (int)fminf(fmaxf(ws, 0.0f), 62.0f);
        fvw[i] = (w >= 0.0f && w < 64.0f) ? 1.0f : 0.0f;
    }

    float prev[8];
    float* srow = sbuf + tid * 49;
#pragma unroll
    for (int i = 0; i < 8; ++i) {
        float cur[8];
#pragma unroll
        for (int j = 0; j < 8; ++j) {
            size_t o00 = (size_t)(b * CCH + c) * (HF * WF) + hi_[i] * WF + wi_[j];
            const float v00 = ft[o00];
            const float v01 = ft[o00 + 1];
            const float v10 = ft[o00 + WF];
            const float v11 = ft[o00 + WF + 1];
            const float top = v00 + wr_[j] * (v01 - v00);
            const float bot = v10 + wr_[j] * (v11 - v10);
            const float v   = top + hr_[i] * (bot - top);
            cur[j] = v * (fvh[i] * fvw[j]);
        }
        if (i > 0) {
#pragma unroll
            for (int j = 0; j < 7; ++j)
                srow[(i - 1) * 7 + j] =
                    0.25f * (prev[j] + prev[j + 1] + cur[j] + cur[j + 1]);
        }
#pragma unroll
        for (int j = 0; j < 8; ++j) prev[j] = cur[j];
    }
    __syncthreads();
    float* obase = out + ((size_t)k * CCH + (size_t)chunk * 256) * 49;
    const float4* s4 = reinterpret_cast<const float4*>(sbuf);
    float4*       o4 = reinterpret_cast<float4*>(obase);
    for (int idx = tid; idx < 3136; idx += 256) o4[idx] = s4[idx];
}

extern "C" void kernel_launch(void* const* d_in, const int* in_sizes, int n_in,
                              void* d_out, int out_size, void* d_ws, size_t ws_size,
                              hipStream_t stream) {
    const float* feat = (const float*)d_in[0];
    const float* rois = (const float*)d_in[1];
    float*       out  = (float*)d_out;

    const int B = in_sizes[0] / (CCH * HF * WF);
    const int K = in_sizes[1] / 5;

    const size_t tbytes = (size_t)B * CCH * HF * WF * sizeof(unsigned short);
    if (ws_size >= tbytes) {
        unsigned short* ftr = (unsigned short*)d_ws;
        dim3 tg((HF * WF) / 32, CCH / 32, B);
        nchw_to_nhwc_bf16<<<tg, 256, 0, stream>>>(feat, ftr);
        roialign_bf16<<<K * 2, 256, 0, stream>>>(ftr, rois, out);
    } else {
        roialign_f32_nchw<<<K * 2, 256, 0, stream>>>(feat, rois, out);
    }
}

// Round 7
// 70.817 us; speedup vs baseline: 6.2693x; 1.0190x over previous
//
#include <hip/hip_runtime.h>

#define HF 64
#define WF 64
#define CCH 512

typedef float f32x4 __attribute__((ext_vector_type(4)));

// f32 -> bf16 round-to-nearest-even
__device__ __forceinline__ unsigned short f32_to_bf16(float f) {
    unsigned int x = __float_as_uint(f);
    unsigned int r = (x + 0x7FFFu + ((x >> 16) & 1u)) >> 16;
    return (unsigned short)r;
}
__device__ __forceinline__ float bf16_to_f32(unsigned short u) {
    return __uint_as_float(((unsigned int)u) << 16);
}

// ---------------- transpose+convert NCHW f32 -> NHWC bf16 -------------------
// NOTE: stores here stay NORMAL (cached) — this bf16 tensor is the gather
// working set and we want it resident in L2.
__global__ __launch_bounds__(256) void nchw_to_nhwc_bf16(const float* __restrict__ src,
                                                         unsigned short* __restrict__ dst) {
    __shared__ float tile[32][33];
    const int hw0 = blockIdx.x * 32;
    const int c0  = blockIdx.y * 32;
    const int b   = blockIdx.z;
    const int tx  = threadIdx.x & 31;
    const int ty  = threadIdx.x >> 5;   // 0..7
    const float*    s = src + (size_t)b * CCH * (HF * WF);
    unsigned short* d = dst + (size_t)b * (HF * WF) * CCH;
#pragma unroll
    for (int i = 0; i < 32; i += 8)
        tile[ty + i][tx] = s[(size_t)(c0 + ty + i) * (HF * WF) + hw0 + tx];
    __syncthreads();
#pragma unroll
    for (int i = 0; i < 32; i += 8)
        d[(size_t)(hw0 + ty + i) * CCH + c0 + tx] = f32_to_bf16(tile[tx][ty + i]);
}

// ---------------- main RoIAlign+avg kernel (NHWC bf16 gather) ---------------
// One block = (roi k, channel chunk of 256). Thread = one channel.
// NOTE (R5 post-mortem): output tile MUST stay f32 in LDS. Staging it as bf16
// (25 KB) regressed 73 -> 444 us (mechanism unidentified). Do not retry.
// R7 single change vs R6: non-temporal output stores (keep 196 MB write
// stream out of L2 so the 8.4 MB bf16 feature set stays L2-resident).
__global__ __launch_bounds__(256) void roialign_bf16(const unsigned short* __restrict__ ft,
                                                     const float* __restrict__ rois,
                                                     float* __restrict__ out) {
    __shared__ __align__(16) float sbuf[256 * 49];

    const int blk   = blockIdx.x;
    const int k     = blk >> 1;
    const int chunk = blk & 1;
    const int tid   = threadIdx.x;
    const int c     = chunk * 256 + tid;

    const float* r = rois + (size_t)k * 5;
    const int   b  = (int)r[0];
    const float x1 = r[1] * 0.0625f;
    const float y1 = r[2] * 0.0625f;
    const float x2 = r[3] * 0.0625f;
    const float y2 = r[4] * 0.0625f;
    const float bin_h = fmaxf(y2 - y1, 0.0f) / 7.0f;
    const float bin_w = fmaxf(x2 - x1, 0.0f) / 7.0f;

    int   hi_[8]; float hr_[8]; float fvh[8];
    int   wi_[8]; float wr_[8]; float fvw[8];
#pragma unroll
    for (int i = 0; i < 8; ++i) {
        float h  = y1 + (float)i * bin_h;
        float hs = fminf(floorf(h), 62.0f);
        hr_[i]   = h - hs;
        hi_[i]   = (int)fminf(fmaxf(hs, 0.0f), 62.0f);
        fvh[i]   = (h >= 0.0f && h < 64.0f) ? 1.0f : 0.0f;
        float w  = x1 + (float)i * bin_w;
        float ws = fminf(floorf(w), 62.0f);
        wr_[i]   = w - ws;
        wi_[i]   = (int)fminf(fmaxf(ws, 0.0f), 62.0f);
        fvw[i]   = (w >= 0.0f && w < 64.0f) ? 1.0f : 0.0f;
    }

    float  prev[8];
    float* srow = sbuf + tid * 49;

#pragma unroll
    for (int i = 0; i < 8; ++i) {
        float cur[8];
#pragma unroll
        for (int j = 0; j < 8; ++j) {
            const unsigned int o00 =
                (unsigned int)(((b * HF + hi_[i]) * WF + wi_[j]) * CCH + c);
            const float v00 = bf16_to_f32(ft[o00]);
            const float v01 = bf16_to_f32(ft[o00 + CCH]);
            const float v10 = bf16_to_f32(ft[o00 + WF * CCH]);
            const float v11 = bf16_to_f32(ft[o00 + WF * CCH + CCH]);
            const float top = v00 + wr_[j] * (v01 - v00);
            const float bot = v10 + wr_[j] * (v11 - v10);
            const float v   = top + hr_[i] * (bot - top);
            cur[j] = v * (fvh[i] * fvw[j]);
        }
        if (i > 0) {
#pragma unroll
            for (int j = 0; j < 7; ++j)
                srow[(i - 1) * 7 + j] =
                    0.25f * (prev[j] + prev[j + 1] + cur[j] + cur[j + 1]);
        }
#pragma unroll
        for (int j = 0; j < 8; ++j) prev[j] = cur[j];
    }

    __syncthreads();

    // coalesced NON-TEMPORAL writeout of the 256x49 f32 tile (3136 x 16B)
    float* obase = out + ((size_t)k * CCH + (size_t)chunk * 256) * 49;
    const f32x4* s4 = reinterpret_cast<const f32x4*>(sbuf);
    f32x4*       o4 = reinterpret_cast<f32x4*>(obase);
    for (int idx = tid; idx < 3136; idx += 256)
        __builtin_nontemporal_store(s4[idx], &o4[idx]);
}

// ---------------- fallback: direct NCHW f32 (if ws too small) ---------------
__global__ __launch_bounds__(256) void roialign_f32_nchw(const float* __restrict__ ft,
                                                         const float* __restrict__ rois,
                                                         float* __restrict__ out) {
    __shared__ __align__(16) float sbuf[256 * 49];
    const int blk   = blockIdx.x;
    const int k     = blk >> 1;
    const int chunk = blk & 1;
    const int tid   = threadIdx.x;
    const int c     = chunk * 256 + tid;

    const float* r = rois + (size_t)k * 5;
    const int   b  = (int)r[0];
    const float x1 = r[1] * 0.0625f;
    const float y1 = r[2] * 0.0625f;
    const float x2 = r[3] * 0.0625f;
    const float y2 = r[4] * 0.0625f;
    const float bin_h = fmaxf(y2 - y1, 0.0f) / 7.0f;
    const float bin_w = fmaxf(x2 - x1, 0.0f) / 7.0f;

    int hi_[8]; float hr_[8]; float fvh[8];
    int wi_[8]; float wr_[8]; float fvw[8];
#pragma unroll
    for (int i = 0; i < 8; ++i) {
        float h  = y1 + (float)i * bin_h;
        float hs = fminf(floorf(h), 62.0f);
        hr_[i] = h - hs;
        hi_[i] = (int)fminf(fmaxf(hs, 0.0f), 62.0f);
        fvh[i] = (h >= 0.0f && h < 64.0f) ? 1.0f : 0.0f;
        float w  = x1 + (float)i * bin_w;
        float ws = fminf(floorf(w), 62.0f);
        wr_[i] = w - ws;
        wi_[i] = (int)fminf(fmaxf(ws, 0.0f), 62.0f);
        fvw[i] = (w >= 0.0f && w < 64.0f) ? 1.0f : 0.0f;
    }

    float prev[8];
    float* srow = sbuf + tid * 49;
#pragma unroll
    for (int i = 0; i < 8; ++i) {
        float cur[8];
#pragma unroll
        for (int j = 0; j < 8; ++j) {
            size_t o00 = (size_t)(b * CCH + c) * (HF * WF) + hi_[i] * WF + wi_[j];
            const float v00 = ft[o00];
            const float v01 = ft[o00 + 1];
            const float v10 = ft[o00 + WF];
            const float v11 = ft[o00 + WF + 1];
            const float top = v00 + wr_[j] * (v01 - v00);
            const float bot = v10 + wr_[j] * (v11 - v10);
            const float v   = top + hr_[i] * (bot - top);
            cur[j] = v * (fvh[i] * fvw[j]);
        }
        if (i > 0) {
#pragma unroll
            for (int j = 0; j < 7; ++j)
                srow[(i - 1) * 7 + j] =
                    0.25f * (prev[j] + prev[j + 1] + cur[j] + cur[j + 1]);
        }
#pragma unroll
        for (int j = 0; j < 8; ++j) prev[j] = cur[j];
    }
    __syncthreads();
    float* obase = out + ((size_t)k * CCH + (size_t)chunk * 256) * 49;
    const f32x4* s4 = reinterpret_cast<const f32x4*>(sbuf);
    f32x4*       o4 = reinterpret_cast<f32x4*>(obase);
    for (int idx = tid; idx < 3136; idx += 256) o4[idx] = s4[idx];
}

extern "C" void kernel_launch(void* const* d_in, const int* in_sizes, int n_in,
                              void* d_out, int out_size, void* d_ws, size_t ws_size,
                              hipStream_t stream) {
    const float* feat = (const float*)d_in[0];
    const float* rois = (const float*)d_in[1];
    float*       out  = (float*)d_out;

    const int B = in_sizes[0] / (CCH * HF * WF);
    const int K = in_sizes[1] / 5;

    const size_t tbytes = (size_t)B * CCH * HF * WF * sizeof(unsigned short);
    if (ws_size >= tbytes) {
        unsigned short* ftr = (unsigned short*)d_ws;
        dim3 tg((HF * WF) / 32, CCH / 32, B);
        nchw_to_nhwc_bf16<<<tg, 256, 0, stream>>>(feat, ftr);
        roialign_bf16<<<K * 2, 256, 0, stream>>>(ftr, rois, out);
    } else {
        roialign_f32_nchw<<<K * 2, 256, 0, stream>>>(feat, rois, out);
    }
}